// Round 4
// baseline (1285.370 us; speedup 1.0000x reference)
//
#include <hip/hip_runtime.h>

#define TPB   512
#define CDIM  192
#define LDX   200   // shorts; row stride 400B ≡ 4 words mod 32 -> 2-way (free)
#define LDV   72    // shorts; 144B ≡ 4 words mod 32
#define SCALE 0.07216878364870323f  // 1/sqrt(192)
#define EPSF  1e-12f

using short8 = __attribute__((ext_vector_type(8))) short;
using f32x4  = __attribute__((ext_vector_type(4))) float;

__device__ __forceinline__ unsigned short f2b(float f) {
  union { float f; unsigned u; } a; a.f = f;
  unsigned u = a.u;
  u += 0x7fffu + ((u >> 16) & 1u);
  return (unsigned short)(u >> 16);
}
__device__ __forceinline__ float b2f(unsigned short h) {
  union { unsigned u; float f; } a; a.u = ((unsigned)h) << 16;
  return a.f;
}
__device__ __forceinline__ unsigned pack2(float x, float y) {
  return (unsigned)f2b(x) | ((unsigned)f2b(y) << 16);
}
#define MFMA(a, b, c) __builtin_amdgcn_mfma_f32_16x16x32_bf16((a), (b), (c), 0, 0, 0)

// ---- pre-kernel: cast weights f32 -> bf16 into workspace ----
#define NWQ  36864
#define NWKV 73728
#define NWP  36864
__global__ void cvt_weights(const float* __restrict__ Wq, const float* __restrict__ Wkv,
                            const float* __restrict__ Wp, unsigned short* __restrict__ o) {
  int i = blockIdx.x * blockDim.x + threadIdx.x;
  if (i < NWQ) o[i] = f2b(Wq[i]);
  else if (i < NWQ + NWKV) o[i] = f2b(Wkv[i - NWQ]);
  else if (i < NWQ + NWKV + NWP) o[i] = f2b(Wp[i - NWQ - NWKV]);
}

__global__ __launch_bounds__(TPB, 4) void wa_v4(
    const float* __restrict__ qx, const float* __restrict__ kvx,
    const float* __restrict__ pos,
    const float* __restrict__ bq, const float* __restrict__ bkv,
    const float* __restrict__ bp,
    const unsigned short* __restrict__ Wqb, const unsigned short* __restrict__ Wkvb,
    const unsigned short* __restrict__ Wpb,
    float* __restrict__ out, int BKV)
{
  __shared__ __align__(16) unsigned short sQ[64 * LDX];    // Q (normalized) -> x
  __shared__ __align__(16) unsigned short sK[64 * LDX];    // K (normalized)
  __shared__ __align__(16) unsigned short sVt[CDIM * LDV]; // V^T [vcol][kvrow]

  const int tid = threadIdx.x;
  const int wid = tid >> 6;
  const int l15 = (tid & 63) & 15;
  const int l4  = (tid & 63) >> 4;
  const int b   = blockIdx.x;
  const size_t qoff  = (size_t)b * (64 * CDIM);
  const size_t kvoff = (size_t)(b % BKV) * (64 * CDIM);

  // ============ Phase 1: projections (A-frags straight from global, B-frags from weights) ============
  if (wid < 4) {
    // ---- q-projection, m-tile = wid ----
    const int m = wid;
    const float* src = qx + qoff + (size_t)(16 * m + l15) * CDIM + 8 * l4;
    const float* ps  = pos + (size_t)(16 * m + l15) * CDIM + 8 * l4;
    short8 A[6];
    #pragma unroll
    for (int ks = 0; ks < 6; ++ks) {
      float4 x0 = *(const float4*)(src + ks * 32);
      float4 x1 = *(const float4*)(src + ks * 32 + 4);
      float4 p0 = *(const float4*)(ps + ks * 32);
      float4 p1 = *(const float4*)(ps + ks * 32 + 4);
      short8 a;
      a[0] = (short)f2b(x0.x + p0.x); a[1] = (short)f2b(x0.y + p0.y);
      a[2] = (short)f2b(x0.z + p0.z); a[3] = (short)f2b(x0.w + p0.w);
      a[4] = (short)f2b(x1.x + p1.x); a[5] = (short)f2b(x1.y + p1.y);
      a[6] = (short)f2b(x1.z + p1.z); a[7] = (short)f2b(x1.w + p1.w);
      A[ks] = a;
    }
    f32x4 acc[12];
    #pragma unroll
    for (int nn = 0; nn < 12; ++nn) {
      float bv = bq[nn * 16 + l15];
      acc[nn] = f32x4{bv, bv, bv, bv};
    }
    #pragma unroll
    for (int ks = 0; ks < 6; ++ks) {
      #pragma unroll
      for (int nn = 0; nn < 12; ++nn) {
        short8 bb = *(const short8*)&Wqb[(size_t)(nn * 16 + l15) * CDIM + ks * 32 + 8 * l4];
        acc[nn] = MFMA(A[ks], bb, acc[nn]);
      }
    }
    #pragma unroll
    for (int nn = 0; nn < 12; ++nn)
      #pragma unroll
      for (int r = 0; r < 4; ++r)
        sQ[(16 * m + 4 * l4 + r) * LDX + nn * 16 + l15] = f2b(acc[nn][r]);
  } else {
    // ---- kv-projection, m-tile = wid-4, two passes of 12 n-tiles ----
    const int m = wid - 4;
    const float* src = kvx + kvoff + (size_t)(16 * m + l15) * CDIM + 8 * l4;
    short8 A[6];
    #pragma unroll
    for (int ks = 0; ks < 6; ++ks) {
      float4 x0 = *(const float4*)(src + ks * 32);
      float4 x1 = *(const float4*)(src + ks * 32 + 4);
      short8 a;
      a[0] = (short)f2b(x0.x); a[1] = (short)f2b(x0.y);
      a[2] = (short)f2b(x0.z); a[3] = (short)f2b(x0.w);
      a[4] = (short)f2b(x1.x); a[5] = (short)f2b(x1.y);
      a[6] = (short)f2b(x1.z); a[7] = (short)f2b(x1.w);
      A[ks] = a;
    }
    #pragma unroll
    for (int half = 0; half < 2; ++half) {
      f32x4 acc[12];
      #pragma unroll
      for (int nn = 0; nn < 12; ++nn) {
        float bv = bkv[(half * 12 + nn) * 16 + l15];
        acc[nn] = f32x4{bv, bv, bv, bv};
      }
      #pragma unroll
      for (int ks = 0; ks < 6; ++ks) {
        #pragma unroll
        for (int nn = 0; nn < 12; ++nn) {
          short8 bb = *(const short8*)&Wkvb[(size_t)((half * 12 + nn) * 16 + l15) * CDIM + ks * 32 + 8 * l4];
          acc[nn] = MFMA(A[ks], bb, acc[nn]);
        }
      }
      #pragma unroll
      for (int nn = 0; nn < 12; ++nn) {
        int colg = (half * 12 + nn) * 16 + l15;
        #pragma unroll
        for (int r = 0; r < 4; ++r) {
          int row = 16 * m + 4 * l4 + r;
          unsigned short hv = f2b(acc[nn][r]);
          if (colg < CDIM) sK[row * LDX + colg] = hv;
          else             sVt[(colg - CDIM) * LDV + row] = hv;
        }
      }
    }
  }
  __syncthreads();

  // ============ Phase 2: fold norms into LDS: Q *= SCALE/||q||, K *= 1/||k|| ============
  for (int t = tid; t < 768; t += TPB) {
    const int isK = t >= 384;
    const int idx = isK ? (t - 384) : t;
    const int h = idx >> 6, r = idx & 63;
    unsigned short* base = (isK ? sK : sQ) + r * LDX + h * 32;
    short8 v[4];
    float ss = 0.f;
    #pragma unroll
    for (int g = 0; g < 4; ++g) {
      v[g] = *(const short8*)&base[g * 8];
      #pragma unroll
      for (int j = 0; j < 8; ++j) { float f = b2f((unsigned short)v[g][j]); ss += f * f; }
    }
    float sc = (isK ? 1.0f : SCALE) / fmaxf(sqrtf(ss), EPSF);
    #pragma unroll
    for (int g = 0; g < 4; ++g) {
      short8 w;
      #pragma unroll
      for (int j = 0; j < 8; ++j) w[j] = (short)f2b(b2f((unsigned short)v[g][j]) * sc);
      *(short8*)&base[g * 8] = w;
    }
  }
  __syncthreads();

  // ============ Phase 3: attention (barrier-free; S^T via swapped QK, P in-register) ============
  {
    const int a_m  = wid & 3;       // q-tile
    const int a_hh = wid >> 2;      // head parity
    const int srcA = l15 + 32 * (l4 & 1);
    const int srcB = srcA + 16;
    const int sel  = l4 >> 1;
    #pragma unroll
    for (int hp = 0; hp < 3; ++hp) {
      const int h = 2 * hp + a_hh;
      // QK^T (swapped): A = K rows, B = Q cols -> S^T; lane holds S[q=16m+l15][k=16n+4l4+r]
      short8 bqf = *(const short8*)&sQ[(16 * a_m + l15) * LDX + h * 32 + 8 * l4];
      f32x4 c[4];
      #pragma unroll
      for (int n = 0; n < 4; ++n) {
        short8 ak = *(const short8*)&sK[(16 * n + l15) * LDX + h * 32 + 8 * l4];
        f32x4 z = f32x4{0.f, 0.f, 0.f, 0.f};
        c[n] = MFMA(ak, bqf, z);
      }
      // softmax over k (16 in-lane + lanes l15+{0,16,32,48})
      float mx = c[0][0];
      #pragma unroll
      for (int n = 0; n < 4; ++n)
        #pragma unroll
        for (int r = 0; r < 4; ++r) mx = fmaxf(mx, c[n][r]);
      mx = fmaxf(mx, __shfl_xor(mx, 16));
      mx = fmaxf(mx, __shfl_xor(mx, 32));
      float sum = 0.f;
      #pragma unroll
      for (int n = 0; n < 4; ++n)
        #pragma unroll
        for (int r = 0; r < 4; ++r) { c[n][r] = __expf(c[n][r] - mx); sum += c[n][r]; }
      sum += __shfl_xor(sum, 16);
      sum += __shfl_xor(sum, 32);
      const float inv = 1.0f / sum;
      unsigned pk[4][2];
      #pragma unroll
      for (int n = 0; n < 4; ++n) {
        pk[n][0] = pack2(c[n][0] * inv, c[n][1] * inv);
        pk[n][1] = pack2(c[n][2] * inv, c[n][3] * inv);
      }
      // redistribute P into PV A-fragments (k = 32c + 8*l4 + j)
      short8 pa[2];
      #pragma unroll
      for (int cc = 0; cc < 2; ++cc) {
        unsigned a00 = (unsigned)__shfl((int)pk[2 * cc][0], srcA);
        unsigned a01 = (unsigned)__shfl((int)pk[2 * cc][1], srcA);
        unsigned a10 = (unsigned)__shfl((int)pk[2 * cc + 1][0], srcA);
        unsigned a11 = (unsigned)__shfl((int)pk[2 * cc + 1][1], srcA);
        unsigned b00 = (unsigned)__shfl((int)pk[2 * cc][0], srcB);
        unsigned b01 = (unsigned)__shfl((int)pk[2 * cc][1], srcB);
        unsigned b10 = (unsigned)__shfl((int)pk[2 * cc + 1][0], srcB);
        unsigned b11 = (unsigned)__shfl((int)pk[2 * cc + 1][1], srcB);
        union { uint4 u; short8 s; } uu;
        uu.u.x = sel ? a10 : a00;
        uu.u.y = sel ? a11 : a01;
        uu.u.z = sel ? b10 : b00;
        uu.u.w = sel ? b11 : b01;
        pa[cc] = uu.s;
      }
      // PV: x-tile n (cols h*32+16n+l15), k chained over 2 chunks
      #pragma unroll
      for (int n = 0; n < 2; ++n) {
        f32x4 cx = f32x4{0.f, 0.f, 0.f, 0.f};
        #pragma unroll
        for (int cc = 0; cc < 2; ++cc) {
          short8 bv = *(const short8*)&sVt[(h * 32 + 16 * n + l15) * LDV + 32 * cc + 8 * l4];
          cx = MFMA(pa[cc], bv, cx);
        }
        #pragma unroll
        for (int r = 0; r < 4; ++r)
          sQ[(16 * a_m + 4 * l4 + r) * LDX + h * 32 + 16 * n + l15] = f2b(cx[r]);
      }
    }
  }
  __syncthreads();

  // ============ Phase 4: out projection ============
  {
    const int mw = wid & 3;
    const int ng = (wid >> 2) * 6;
    f32x4 acc[6];
    #pragma unroll
    for (int nn = 0; nn < 6; ++nn) {
      float bv = bp[(ng + nn) * 16 + l15];
      acc[nn] = f32x4{bv, bv, bv, bv};
    }
    #pragma unroll
    for (int ks = 0; ks < 6; ++ks) {
      short8 a = *(const short8*)&sQ[(16 * mw + l15) * LDX + ks * 32 + 8 * l4];
      #pragma unroll
      for (int nn = 0; nn < 6; ++nn) {
        short8 bb = *(const short8*)&Wpb[(size_t)((ng + nn) * 16 + l15) * CDIM + ks * 32 + 8 * l4];
        acc[nn] = MFMA(a, bb, acc[nn]);
      }
    }
    #pragma unroll
    for (int nn = 0; nn < 6; ++nn)
      #pragma unroll
      for (int r = 0; r < 4; ++r)
        out[qoff + (size_t)(16 * mw + 4 * l4 + r) * CDIM + (ng + nn) * 16 + l15] = acc[nn][r];
  }
}

extern "C" void kernel_launch(void* const* d_in, const int* in_sizes, int n_in,
                              void* d_out, int out_size, void* d_ws, size_t ws_size,
                              hipStream_t stream) {
  const float* qx  = (const float*)d_in[0];
  const float* kvx = (const float*)d_in[1];
  const float* pos = (const float*)d_in[2];
  const float* Wq  = (const float*)d_in[3];
  const float* bq  = (const float*)d_in[4];
  const float* Wkv = (const float*)d_in[5];
  const float* bkv = (const float*)d_in[6];
  const float* Wp  = (const float*)d_in[7];
  const float* bp  = (const float*)d_in[8];
  float* out = (float*)d_out;
  unsigned short* wsb = (unsigned short*)d_ws;

  const int BQ  = in_sizes[0] / (64 * CDIM);
  const int BKV = in_sizes[1] / (64 * CDIM);

  const int ncvt = NWQ + NWKV + NWP;
  cvt_weights<<<(ncvt + 255) / 256, 256, 0, stream>>>(Wq, Wkv, Wp, wsb);

  wa_v4<<<BQ, TPB, 0, stream>>>(qx, kvx, pos, bq, bkv, bp,
                                wsb, wsb + NWQ, wsb + NWQ + NWKV, out, BKV);
}

// Round 5
// 1273.676 us; speedup vs baseline: 1.0092x; 1.0092x over previous
//
#include <hip/hip_runtime.h>
#include <hip/hip_bf16.h>

#define TPB   512
#define CDIM  192
#define LDX   200   // shorts; row stride 400B ≡ 4 words mod 32 -> benign
#define LDV   72    // shorts; 144B ≡ 4 words mod 32
#define SCALE 0.07216878364870323f  // 1/sqrt(192)
#define EPSF  1e-12f

using short8 = __attribute__((ext_vector_type(8))) short;
using f32x4  = __attribute__((ext_vector_type(4))) float;
using us4    = __attribute__((ext_vector_type(4))) unsigned short;

__device__ __forceinline__ unsigned short hc(float f) {
  __hip_bfloat16 h = __float2bfloat16(f);   // RNE, hw cvt (compiler packs pairs)
  unsigned short u; __builtin_memcpy(&u, &h, 2); return u;
}
__device__ __forceinline__ float b2f(unsigned short h) {
  union { unsigned u; float f; } a; a.u = ((unsigned)h) << 16;
  return a.f;
}
__device__ __forceinline__ unsigned pack2(float x, float y) {
  return (unsigned)hc(x) | ((unsigned)hc(y) << 16);
}
#define MFMA(a, b, c) __builtin_amdgcn_mfma_f32_16x16x32_bf16((a), (b), (c), 0, 0, 0)

// ---- pre-kernel: cast weights f32 -> bf16 into workspace ----
#define NWQ  36864
#define NWKV 73728
#define NWP  36864
__global__ void cvt_weights(const float* __restrict__ Wq, const float* __restrict__ Wkv,
                            const float* __restrict__ Wp, unsigned short* __restrict__ o) {
  int i = blockIdx.x * blockDim.x + threadIdx.x;
  if (i < NWQ) o[i] = hc(Wq[i]);
  else if (i < NWQ + NWKV) o[i] = hc(Wkv[i - NWQ]);
  else if (i < NWQ + NWKV + NWP) o[i] = hc(Wp[i - NWQ - NWKV]);
}

__global__ __launch_bounds__(TPB) void wa_v5(
    const float* __restrict__ qx, const float* __restrict__ kvx,
    const float* __restrict__ pos,
    const float* __restrict__ bq, const float* __restrict__ bkv,
    const float* __restrict__ bp,
    const unsigned short* __restrict__ Wqb, const unsigned short* __restrict__ Wkvb,
    const unsigned short* __restrict__ Wpb,
    float* __restrict__ out, int BKV)
{
  __shared__ __align__(16) unsigned short sQ[64 * LDX];    // qx staged -> Q(normalized*SCALE) -> x
  __shared__ __align__(16) unsigned short sK[64 * LDX];    // K (normalized)
  __shared__ __align__(16) unsigned short sVt[CDIM * LDV]; // kvx staged (flat) -> V^T [vcol][kvrow]

  const int tid = threadIdx.x;
  const int wid = tid >> 6;
  const int l15 = (tid & 63) & 15;
  const int l4  = (tid & 63) >> 4;
  const int b   = blockIdx.x;
  const size_t qoff  = (size_t)b * (64 * CDIM);
  const size_t kvoff = (size_t)(b % BKV) * (64 * CDIM);

  // ============ Phase 1: coalesced staging (qx+pos -> sQ, kvx -> sVt area) ============
  {
    const float4* gq = (const float4*)(qx + qoff);
    const float4* gk = (const float4*)(kvx + kvoff);
    const float4* p4 = (const float4*)pos;
    #pragma unroll
    for (int t = 0; t < 6; ++t) {
      int e = tid + t * TPB, row = e / 48, c4 = e % 48;
      float4 a = gq[e], p = p4[e], k = gk[e];
      us4 wq, wk;
      wq.x = hc(a.x + p.x); wq.y = hc(a.y + p.y); wq.z = hc(a.z + p.z); wq.w = hc(a.w + p.w);
      wk.x = hc(k.x); wk.y = hc(k.y); wk.z = hc(k.z); wk.w = hc(k.w);
      *(us4*)&sQ[row * LDX + c4 * 4] = wq;
      *(us4*)&sVt[row * LDX + c4 * 4] = wk;
    }
  }
  __syncthreads();

  // ============ Phase 2: pull A-fragments LDS -> regs (enables in-place overwrite) ============
  short8 A[6];
  {
    const unsigned short* src = (wid < 4) ? &sQ[(16 * wid + l15) * LDX]
                                          : &sVt[(16 * (wid - 4) + l15) * LDX];
    #pragma unroll
    for (int ks = 0; ks < 6; ++ks) A[ks] = *(const short8*)&src[ks * 32 + 8 * l4];
  }
  __syncthreads();

  // ============ Phase 3: projections + f32-accumulator norm folding ============
  if (wid < 4) {
    // ---- q-proj, m-tile = wid; fold SCALE/||q|| before cast ----
    const int m = wid;
    f32x4 acc[12];
    #pragma unroll
    for (int nn = 0; nn < 12; ++nn) {
      float bv = bq[nn * 16 + l15];
      acc[nn] = f32x4{bv, bv, bv, bv};
    }
    #pragma unroll
    for (int ks = 0; ks < 6; ++ks) {
      #pragma unroll
      for (int nn = 0; nn < 12; ++nn) {
        short8 bb = *(const short8*)&Wqb[(size_t)(nn * 16 + l15) * CDIM + ks * 32 + 8 * l4];
        acc[nn] = MFMA(A[ks], bb, acc[nn]);
      }
    }
    #pragma unroll
    for (int h = 0; h < 6; ++h) {
      #pragma unroll
      for (int r = 0; r < 4; ++r) {
        float s = acc[2 * h][r] * acc[2 * h][r] + acc[2 * h + 1][r] * acc[2 * h + 1][r];
        s += __shfl_xor(s, 1); s += __shfl_xor(s, 2); s += __shfl_xor(s, 4); s += __shfl_xor(s, 8);
        float sc = SCALE / fmaxf(sqrtf(s), EPSF);
        int row = (16 * m + 4 * l4 + r) * LDX;
        sQ[row + (2 * h) * 16 + l15]     = hc(acc[2 * h][r] * sc);
        sQ[row + (2 * h + 1) * 16 + l15] = hc(acc[2 * h + 1][r] * sc);
      }
    }
  } else {
    // ---- kv-proj, m-tile = wid-4 ----
    const int m = wid - 4;
    {   // K half (cols 0..191): fold 1/||k|| before cast
      f32x4 acc[12];
      #pragma unroll
      for (int nn = 0; nn < 12; ++nn) {
        float bv = bkv[nn * 16 + l15];
        acc[nn] = f32x4{bv, bv, bv, bv};
      }
      #pragma unroll
      for (int ks = 0; ks < 6; ++ks) {
        #pragma unroll
        for (int nn = 0; nn < 12; ++nn) {
          short8 bb = *(const short8*)&Wkvb[(size_t)(nn * 16 + l15) * CDIM + ks * 32 + 8 * l4];
          acc[nn] = MFMA(A[ks], bb, acc[nn]);
        }
      }
      #pragma unroll
      for (int h = 0; h < 6; ++h) {
        #pragma unroll
        for (int r = 0; r < 4; ++r) {
          float s = acc[2 * h][r] * acc[2 * h][r] + acc[2 * h + 1][r] * acc[2 * h + 1][r];
          s += __shfl_xor(s, 1); s += __shfl_xor(s, 2); s += __shfl_xor(s, 4); s += __shfl_xor(s, 8);
          float sc = 1.0f / fmaxf(sqrtf(s), EPSF);
          int row = (16 * m + 4 * l4 + r) * LDX;
          sK[row + (2 * h) * 16 + l15]     = hc(acc[2 * h][r] * sc);
          sK[row + (2 * h + 1) * 16 + l15] = hc(acc[2 * h + 1][r] * sc);
        }
      }
    }
    {   // V half (cols 192..383): transpose-store into sVt
      f32x4 acc[12];
      #pragma unroll
      for (int nn = 0; nn < 12; ++nn) {
        float bv = bkv[(12 + nn) * 16 + l15];
        acc[nn] = f32x4{bv, bv, bv, bv};
      }
      #pragma unroll
      for (int ks = 0; ks < 6; ++ks) {
        #pragma unroll
        for (int nn = 0; nn < 12; ++nn) {
          short8 bb = *(const short8*)&Wkvb[(size_t)((12 + nn) * 16 + l15) * CDIM + ks * 32 + 8 * l4];
          acc[nn] = MFMA(A[ks], bb, acc[nn]);
        }
      }
      #pragma unroll
      for (int nn = 0; nn < 12; ++nn) {
        int vcol = nn * 16 + l15;
        #pragma unroll
        for (int r = 0; r < 4; ++r)
          sVt[vcol * LDV + 16 * m + 4 * l4 + r] = hc(acc[nn][r]);
      }
    }
  }
  __syncthreads();

  // ============ Phase 4: attention (barrier-free; S^T via swapped QK, P in-register) ============
  {
    const int a_m  = wid & 3;       // q-tile
    const int a_hh = wid >> 2;      // head parity
    const int srcA = l15 + 32 * (l4 & 1);
    const int srcB = srcA + 16;
    const int sel  = l4 >> 1;
    #pragma unroll
    for (int hp = 0; hp < 3; ++hp) {
      const int h = 2 * hp + a_hh;
      short8 bqf = *(const short8*)&sQ[(16 * a_m + l15) * LDX + h * 32 + 8 * l4];
      f32x4 c[4];
      #pragma unroll
      for (int n = 0; n < 4; ++n) {
        short8 ak = *(const short8*)&sK[(16 * n + l15) * LDX + h * 32 + 8 * l4];
        f32x4 z = f32x4{0.f, 0.f, 0.f, 0.f};
        c[n] = MFMA(ak, bqf, z);
      }
      // softmax over k (16 in-lane + lane groups l15+{0,16,32,48})
      float mx = c[0][0];
      #pragma unroll
      for (int n = 0; n < 4; ++n)
        #pragma unroll
        for (int r = 0; r < 4; ++r) mx = fmaxf(mx, c[n][r]);
      mx = fmaxf(mx, __shfl_xor(mx, 16));
      mx = fmaxf(mx, __shfl_xor(mx, 32));
      float sum = 0.f;
      #pragma unroll
      for (int n = 0; n < 4; ++n)
        #pragma unroll
        for (int r = 0; r < 4; ++r) { c[n][r] = __expf(c[n][r] - mx); sum += c[n][r]; }
      sum += __shfl_xor(sum, 16);
      sum += __shfl_xor(sum, 32);
      const float inv = 1.0f / sum;
      unsigned pk[4][2];
      #pragma unroll
      for (int n = 0; n < 4; ++n) {
        pk[n][0] = pack2(c[n][0] * inv, c[n][1] * inv);
        pk[n][1] = pack2(c[n][2] * inv, c[n][3] * inv);
      }
      // redistribute P into PV A-fragments (k = 32c + 8*l4 + j)
      short8 pa[2];
      #pragma unroll
      for (int cc = 0; cc < 2; ++cc) {
        unsigned a00 = (unsigned)__shfl((int)pk[2 * cc][0], srcA);
        unsigned a01 = (unsigned)__shfl((int)pk[2 * cc][1], srcA);
        unsigned a10 = (unsigned)__shfl((int)pk[2 * cc + 1][0], srcA);
        unsigned a11 = (unsigned)__shfl((int)pk[2 * cc + 1][1], srcA);
        unsigned b00 = (unsigned)__shfl((int)pk[2 * cc][0], srcB);
        unsigned b01 = (unsigned)__shfl((int)pk[2 * cc][1], srcB);
        unsigned b10 = (unsigned)__shfl((int)pk[2 * cc + 1][0], srcB);
        unsigned b11 = (unsigned)__shfl((int)pk[2 * cc + 1][1], srcB);
        union { uint4 u; short8 s; } uu;
        uu.u.x = sel ? a10 : a00;
        uu.u.y = sel ? a11 : a01;
        uu.u.z = sel ? b10 : b00;
        uu.u.w = sel ? b11 : b01;
        pa[cc] = uu.s;
      }
      // PV: x cols h*32+16n+l15
      #pragma unroll
      for (int n = 0; n < 2; ++n) {
        f32x4 cx = f32x4{0.f, 0.f, 0.f, 0.f};
        #pragma unroll
        for (int cc = 0; cc < 2; ++cc) {
          short8 bv = *(const short8*)&sVt[(h * 32 + 16 * n + l15) * LDV + 32 * cc + 8 * l4];
          cx = MFMA(pa[cc], bv, cx);
        }
        #pragma unroll
        for (int r = 0; r < 4; ++r)
          sQ[(16 * a_m + 4 * l4 + r) * LDX + h * 32 + 16 * n + l15] = hc(cx[r]);
      }
    }
  }
  __syncthreads();

  // ============ Phase 5: out projection ============
  {
    const int mw = wid & 3;
    const int ng = (wid >> 2) * 6;
    f32x4 acc[6];
    #pragma unroll
    for (int nn = 0; nn < 6; ++nn) {
      float bv = bp[(ng + nn) * 16 + l15];
      acc[nn] = f32x4{bv, bv, bv, bv};
    }
    #pragma unroll
    for (int ks = 0; ks < 6; ++ks) {
      short8 a = *(const short8*)&sQ[(16 * mw + l15) * LDX + ks * 32 + 8 * l4];
      #pragma unroll
      for (int nn = 0; nn < 6; ++nn) {
        short8 bb = *(const short8*)&Wpb[(size_t)((ng + nn) * 16 + l15) * CDIM + ks * 32 + 8 * l4];
        acc[nn] = MFMA(a, bb, acc[nn]);
      }
    }
    #pragma unroll
    for (int nn = 0; nn < 6; ++nn)
      #pragma unroll
      for (int r = 0; r < 4; ++r)
        out[qoff + (size_t)(16 * mw + 4 * l4 + r) * CDIM + (ng + nn) * 16 + l15] = acc[nn][r];
  }
}

extern "C" void kernel_launch(void* const* d_in, const int* in_sizes, int n_in,
                              void* d_out, int out_size, void* d_ws, size_t ws_size,
                              hipStream_t stream) {
  const float* qx  = (const float*)d_in[0];
  const float* kvx = (const float*)d_in[1];
  const float* pos = (const float*)d_in[2];
  const float* Wq  = (const float*)d_in[3];
  const float* bq  = (const float*)d_in[4];
  const float* Wkv = (const float*)d_in[5];
  const float* bkv = (const float*)d_in[6];
  const float* Wp  = (const float*)d_in[7];
  const float* bp  = (const float*)d_in[8];
  float* out = (float*)d_out;
  unsigned short* wsb = (unsigned short*)d_ws;

  const int BQ  = in_sizes[0] / (64 * CDIM);
  const int BKV = in_sizes[1] / (64 * CDIM);

  const int ncvt = NWQ + NWKV + NWP;
  cvt_weights<<<(ncvt + 255) / 256, 256, 0, stream>>>(Wq, Wkv, Wp, wsb);

  wa_v5<<<BQ, TPB, 0, stream>>>(qx, kvx, pos, bq, bkv, bp,
                                wsb, wsb + NWQ, wsb + NWQ + NWKV, out, BKV);
}

// Round 6
// 650.750 us; speedup vs baseline: 1.9752x; 1.9572x over previous
//
#include <hip/hip_runtime.h>
#include <hip/hip_bf16.h>

#define TPB   512
#define CDIM  192
#define LDX   200   // shorts; row stride 400B -> uniform 8-deep banks for b128 frags
#define LDV   72    // shorts; V^T leading dim (144B, 16B-aligned)
#define SCALE 0.07216878364870323f  // 1/sqrt(192)
#define EPSF  1e-12f

using short8 = __attribute__((ext_vector_type(8))) short;
using f32x4  = __attribute__((ext_vector_type(4))) float;
using us4    = __attribute__((ext_vector_type(4))) unsigned short;

__device__ __forceinline__ unsigned short hc(float f) {
  __hip_bfloat16 h = __float2bfloat16(f);
  unsigned short u; __builtin_memcpy(&u, &h, 2); return u;
}
__device__ __forceinline__ float b2f(unsigned short h) {
  union { unsigned u; float f; } a; a.u = ((unsigned)h) << 16;
  return a.f;
}
__device__ __forceinline__ unsigned pack2(float x, float y) {
  return (unsigned)hc(x) | ((unsigned)hc(y) << 16);
}
__device__ __forceinline__ uint2 packa(f32x4 a) {
  return make_uint2(pack2(a[0], a[1]), pack2(a[2], a[3]));
}
#define MFMA(a, b, c) __builtin_amdgcn_mfma_f32_16x16x32_bf16((a), (b), (c), 0, 0, 0)

// ---- pre-kernel: cast weights f32 -> bf16 into workspace ----
#define NWQ  36864
#define NWKV 73728
#define NWP  36864
__global__ void cvt_weights(const float* __restrict__ Wq, const float* __restrict__ Wkv,
                            const float* __restrict__ Wp, unsigned short* __restrict__ o) {
  int i = blockIdx.x * blockDim.x + threadIdx.x;
  if (i < NWQ) o[i] = hc(Wq[i]);
  else if (i < NWQ + NWKV) o[i] = hc(Wkv[i - NWQ]);
  else if (i < NWQ + NWKV + NWP) o[i] = hc(Wp[i - NWQ - NWKV]);
}

__global__ __launch_bounds__(TPB) void wa_v6(
    const float* __restrict__ qx, const float* __restrict__ kvx,
    const float* __restrict__ pos,
    const float* __restrict__ bq, const float* __restrict__ bkv,
    const float* __restrict__ bp,
    const unsigned short* __restrict__ Wqb, const unsigned short* __restrict__ Wkvb,
    const unsigned short* __restrict__ Wpb,
    float* __restrict__ out, int BKV)
{
  __shared__ __align__(16) unsigned short sA[64 * LDX];     // qx+pos staged -> Q(norm) -> x
  __shared__ __align__(16) unsigned short sB[64 * LDX];     // K (norm)
  __shared__ __align__(16) unsigned short sVt[CDIM * LDV];  // kvx staged (flat LDX) -> V^T

  const int tid = threadIdx.x;
  const int wid = tid >> 6;
  const int l15 = (tid & 63) & 15;
  const int l4  = (tid & 63) >> 4;
  const int b   = blockIdx.x;
  const size_t qoff  = (size_t)b * (64 * CDIM);
  const size_t kvoff = (size_t)(b % BKV) * (64 * CDIM);

  // ============ P1: coalesced staging (qx+pos -> sA, kvx -> sVt flat) ============
  {
    const float4* gq = (const float4*)(qx + qoff);
    const float4* gk = (const float4*)(kvx + kvoff);
    const float4* p4 = (const float4*)pos;
    #pragma unroll
    for (int t = 0; t < 6; ++t) {
      int e = tid + t * TPB, row = e / 48, c4 = e % 48;
      float4 a = gq[e], p = p4[e], k = gk[e];
      us4 wq, wk;
      wq.x = hc(a.x + p.x); wq.y = hc(a.y + p.y); wq.z = hc(a.z + p.z); wq.w = hc(a.w + p.w);
      wk.x = hc(k.x); wk.y = hc(k.y); wk.z = hc(k.z); wk.w = hc(k.w);
      *(us4*)&sA[row * LDX + c4 * 4] = wq;
      *(us4*)&sVt[row * LDX + c4 * 4] = wk;
    }
  }
  __syncthreads();

  // ============ P2: all projections; B-frags preloaded & reused over 4 m-tiles ============
  auto ptile = [&](const unsigned short* Ab, const unsigned short* Wrow0, float bv, f32x4* acc) {
    short8 B[6];
    #pragma unroll
    for (int k = 0; k < 6; ++k)
      B[k] = *(const short8*)&Wrow0[(size_t)l15 * CDIM + k * 32 + 8 * l4];
    #pragma unroll
    for (int m = 0; m < 4; ++m) acc[m] = f32x4{bv, bv, bv, bv};
    #pragma unroll
    for (int m = 0; m < 4; ++m)
      #pragma unroll
      for (int k = 0; k < 6; ++k) {
        short8 a = *(const short8*)&Ab[(16 * m + l15) * LDX + k * 32 + 8 * l4];
        acc[m] = MFMA(a, B[k], acc[m]);
      }
  };

  uint2 hqa[4], hqb[4], hva[4], hvb[4];
  const int nqa = (wid < 4) ? wid + 8 : wid - 4;

  {
    f32x4 acc[4];
    // ---- K tiles (write-through to sB) ----
    {
      int n = wid;
      ptile(sVt, Wkvb + (size_t)n * 16 * CDIM, bkv[n * 16 + l15], acc);
      #pragma unroll
      for (int m = 0; m < 4; ++m) {
        int rb = 16 * m + 4 * l4;
        #pragma unroll
        for (int r = 0; r < 4; ++r) sB[(rb + r) * LDX + n * 16 + l15] = hc(acc[m][r]);
      }
      if (wid < 4) {
        n = wid + 8;
        ptile(sVt, Wkvb + (size_t)n * 16 * CDIM, bkv[n * 16 + l15], acc);
        #pragma unroll
        for (int m = 0; m < 4; ++m) {
          int rb = 16 * m + 4 * l4;
          #pragma unroll
          for (int r = 0; r < 4; ++r) sB[(rb + r) * LDX + n * 16 + l15] = hc(acc[m][r]);
        }
      }
    }
    // ---- Q tiles (held packed bf16) ----
    {
      ptile(sA, Wqb + (size_t)nqa * 16 * CDIM, bq[nqa * 16 + l15], acc);
      #pragma unroll
      for (int m = 0; m < 4; ++m) hqa[m] = packa(acc[m]);
      if (wid >= 4) {
        ptile(sA, Wqb + (size_t)wid * 16 * CDIM, bq[wid * 16 + l15], acc);
        #pragma unroll
        for (int m = 0; m < 4; ++m) hqb[m] = packa(acc[m]);
      }
    }
    // ---- V tiles (held packed bf16) ----
    {
      int n = wid;
      ptile(sVt, Wkvb + (size_t)(CDIM + n * 16) * CDIM, bkv[CDIM + n * 16 + l15], acc);
      #pragma unroll
      for (int m = 0; m < 4; ++m) hva[m] = packa(acc[m]);
      if (wid < 4) {
        n = wid + 8;
        ptile(sVt, Wkvb + (size_t)(CDIM + n * 16) * CDIM, bkv[CDIM + n * 16 + l15], acc);
        #pragma unroll
        for (int m = 0; m < 4; ++m) hvb[m] = packa(acc[m]);
      }
    }
  }
  __syncthreads();

  // ============ P3: write held Q (scalar) and V (b64 transposed) ============
  {
    #pragma unroll
    for (int m = 0; m < 4; ++m) {
      int rb = 16 * m + 4 * l4, col = nqa * 16 + l15;
      sA[(rb + 0) * LDX + col] = (unsigned short)(hqa[m].x & 0xffff);
      sA[(rb + 1) * LDX + col] = (unsigned short)(hqa[m].x >> 16);
      sA[(rb + 2) * LDX + col] = (unsigned short)(hqa[m].y & 0xffff);
      sA[(rb + 3) * LDX + col] = (unsigned short)(hqa[m].y >> 16);
    }
    if (wid >= 4) {
      #pragma unroll
      for (int m = 0; m < 4; ++m) {
        int rb = 16 * m + 4 * l4, col = wid * 16 + l15;
        sA[(rb + 0) * LDX + col] = (unsigned short)(hqb[m].x & 0xffff);
        sA[(rb + 1) * LDX + col] = (unsigned short)(hqb[m].x >> 16);
        sA[(rb + 2) * LDX + col] = (unsigned short)(hqb[m].y & 0xffff);
        sA[(rb + 3) * LDX + col] = (unsigned short)(hqb[m].y >> 16);
      }
    }
    #pragma unroll
    for (int m = 0; m < 4; ++m)
      *(uint2*)&sVt[(16 * wid + l15) * LDV + 16 * m + 4 * l4] = hva[m];
    if (wid < 4) {
      #pragma unroll
      for (int m = 0; m < 4; ++m)
        *(uint2*)&sVt[(16 * (wid + 8) + l15) * LDV + 16 * m + 4 * l4] = hvb[m];
    }
  }
  __syncthreads();

  // ============ P4: norm pass (Q *= SCALE/||q_h||, K *= 1/||k_h||) ============
  for (int t = tid; t < 768; t += TPB) {
    const int isK = t >= 384;
    const int idx = isK ? (t - 384) : t;
    const int h = idx >> 6, r = idx & 63;
    unsigned short* base = (isK ? sB : sA) + r * LDX + h * 32;
    short8 v[4];
    float ss = 0.f;
    #pragma unroll
    for (int g = 0; g < 4; ++g) {
      v[g] = *(const short8*)&base[g * 8];
      #pragma unroll
      for (int j = 0; j < 8; ++j) { float f = b2f((unsigned short)v[g][j]); ss += f * f; }
    }
    float sc = (isK ? 1.0f : SCALE) / fmaxf(sqrtf(ss), EPSF);
    #pragma unroll
    for (int g = 0; g < 4; ++g) {
      short8 w;
      #pragma unroll
      for (int j = 0; j < 8; ++j) w[j] = (short)hc(b2f((unsigned short)v[g][j]) * sc);
      *(short8*)&base[g * 8] = w;
    }
  }
  __syncthreads();

  // ============ P5: attention (barrier-free; swapped QK, in-register P) ============
  {
    const int a_m  = wid & 3;
    const int a_hh = wid >> 2;
    const int srcA = l15 + 32 * (l4 & 1);
    const int srcB = srcA + 16;
    const int sel  = l4 >> 1;
    #pragma unroll
    for (int hp = 0; hp < 3; ++hp) {
      const int h = 2 * hp + a_hh;
      short8 bqf = *(const short8*)&sA[(16 * a_m + l15) * LDX + h * 32 + 8 * l4];
      f32x4 c[4];
      #pragma unroll
      for (int n = 0; n < 4; ++n) {
        short8 ak = *(const short8*)&sB[(16 * n + l15) * LDX + h * 32 + 8 * l4];
        f32x4 z = f32x4{0.f, 0.f, 0.f, 0.f};
        c[n] = MFMA(ak, bqf, z);
      }
      float mx = c[0][0];
      #pragma unroll
      for (int n = 0; n < 4; ++n)
        #pragma unroll
        for (int r = 0; r < 4; ++r) mx = fmaxf(mx, c[n][r]);
      mx = fmaxf(mx, __shfl_xor(mx, 16));
      mx = fmaxf(mx, __shfl_xor(mx, 32));
      float sum = 0.f;
      #pragma unroll
      for (int n = 0; n < 4; ++n)
        #pragma unroll
        for (int r = 0; r < 4; ++r) { c[n][r] = __expf(c[n][r] - mx); sum += c[n][r]; }
      sum += __shfl_xor(sum, 16);
      sum += __shfl_xor(sum, 32);
      const float inv = 1.0f / sum;
      unsigned pk[4][2];
      #pragma unroll
      for (int n = 0; n < 4; ++n) {
        pk[n][0] = pack2(c[n][0] * inv, c[n][1] * inv);
        pk[n][1] = pack2(c[n][2] * inv, c[n][3] * inv);
      }
      short8 pa[2];
      #pragma unroll
      for (int cc = 0; cc < 2; ++cc) {
        unsigned a00 = (unsigned)__shfl((int)pk[2 * cc][0], srcA);
        unsigned a01 = (unsigned)__shfl((int)pk[2 * cc][1], srcA);
        unsigned a10 = (unsigned)__shfl((int)pk[2 * cc + 1][0], srcA);
        unsigned a11 = (unsigned)__shfl((int)pk[2 * cc + 1][1], srcA);
        unsigned b00 = (unsigned)__shfl((int)pk[2 * cc][0], srcB);
        unsigned b01 = (unsigned)__shfl((int)pk[2 * cc][1], srcB);
        unsigned b10 = (unsigned)__shfl((int)pk[2 * cc + 1][0], srcB);
        unsigned b11 = (unsigned)__shfl((int)pk[2 * cc + 1][1], srcB);
        union { uint4 u; short8 s; } uu;
        uu.u.x = sel ? a10 : a00;
        uu.u.y = sel ? a11 : a01;
        uu.u.z = sel ? b10 : b00;
        uu.u.w = sel ? b11 : b01;
        pa[cc] = uu.s;
      }
      #pragma unroll
      for (int n = 0; n < 2; ++n) {
        f32x4 cx = f32x4{0.f, 0.f, 0.f, 0.f};
        #pragma unroll
        for (int cc = 0; cc < 2; ++cc) {
          short8 bv = *(const short8*)&sVt[(h * 32 + 16 * n + l15) * LDV + 32 * cc + 8 * l4];
          cx = MFMA(pa[cc], bv, cx);
        }
        #pragma unroll
        for (int r = 0; r < 4; ++r)
          sA[(16 * a_m + 4 * l4 + r) * LDX + h * 32 + 16 * n + l15] = hc(cx[r]);
      }
    }
  }
  __syncthreads();

  // ============ P6: out projection (B-frags preloaded, reused over m) ============
  {
    // primary n-tile = wid, all 4 m-tiles
    {
      short8 B[6];
      #pragma unroll
      for (int k = 0; k < 6; ++k)
        B[k] = *(const short8*)&Wpb[(size_t)(wid * 16 + l15) * CDIM + k * 32 + 8 * l4];
      f32x4 acc[4];
      float bv = bp[wid * 16 + l15];
      #pragma unroll
      for (int m = 0; m < 4; ++m) acc[m] = f32x4{bv, bv, bv, bv};
      #pragma unroll
      for (int m = 0; m < 4; ++m)
        #pragma unroll
        for (int k = 0; k < 6; ++k) {
          short8 a = *(const short8*)&sA[(16 * m + l15) * LDX + k * 32 + 8 * l4];
          acc[m] = MFMA(a, B[k], acc[m]);
        }
      #pragma unroll
      for (int m = 0; m < 4; ++m)
        #pragma unroll
        for (int r = 0; r < 4; ++r)
          out[qoff + (size_t)(16 * m + 4 * l4 + r) * CDIM + wid * 16 + l15] = acc[m][r];
    }
    // secondary n-tile = 8 + (wid>>1), m-tiles {2*(wid&1), 2*(wid&1)+1}
    {
      const int ns = 8 + (wid >> 1);
      const int m0 = 2 * (wid & 1);
      short8 B[6];
      #pragma unroll
      for (int k = 0; k < 6; ++k)
        B[k] = *(const short8*)&Wpb[(size_t)(ns * 16 + l15) * CDIM + k * 32 + 8 * l4];
      f32x4 acc[2];
      float bv = bp[ns * 16 + l15];
      acc[0] = f32x4{bv, bv, bv, bv};
      acc[1] = f32x4{bv, bv, bv, bv};
      #pragma unroll
      for (int mm = 0; mm < 2; ++mm)
        #pragma unroll
        for (int k = 0; k < 6; ++k) {
          short8 a = *(const short8*)&sA[(16 * (m0 + mm) + l15) * LDX + k * 32 + 8 * l4];
          acc[mm] = MFMA(a, B[k], acc[mm]);
        }
      #pragma unroll
      for (int mm = 0; mm < 2; ++mm)
        #pragma unroll
        for (int r = 0; r < 4; ++r)
          out[qoff + (size_t)(16 * (m0 + mm) + 4 * l4 + r) * CDIM + ns * 16 + l15] = acc[mm][r];
    }
  }
}

extern "C" void kernel_launch(void* const* d_in, const int* in_sizes, int n_in,
                              void* d_out, int out_size, void* d_ws, size_t ws_size,
                              hipStream_t stream) {
  const float* qx  = (const float*)d_in[0];
  const float* kvx = (const float*)d_in[1];
  const float* pos = (const float*)d_in[2];
  const float* Wq  = (const float*)d_in[3];
  const float* bq  = (const float*)d_in[4];
  const float* Wkv = (const float*)d_in[5];
  const float* bkv = (const float*)d_in[6];
  const float* Wp  = (const float*)d_in[7];
  const float* bp  = (const float*)d_in[8];
  float* out = (float*)d_out;
  unsigned short* wsb = (unsigned short*)d_ws;

  const int BQ  = in_sizes[0] / (64 * CDIM);
  const int BKV = in_sizes[1] / (64 * CDIM);

  const int ncvt = NWQ + NWKV + NWP;
  cvt_weights<<<(ncvt + 255) / 256, 256, 0, stream>>>(Wq, Wkv, Wp, wsb);

  wa_v6<<<BQ, TPB, 0, stream>>>(qx, kvx, pos, bq, bkv, bp,
                                wsb, wsb + NWQ, wsb + NWQ + NWKV, out, BKV);
}